// Round 1
// baseline (1725.740 us; speedup 1.0000x reference)
//
#include <hip/hip_runtime.h>
#include <math.h>

// Problem constants
#define BB 2
#define N1 65536
#define N2 16384
#define CC 256
#define GG 512
#define NH 8
#define DH 32

// ws layout (float offsets)
#define WS_WF    0         // 512*256 fused mheads1_w@q_w
#define WS_PPART 131072    // 2*128*256 pool partials
#define WS_POOL  196608    // 2*256
#define WS_GLOB  197120    // 2*256
#define WS_KVP   197632    // 2*8*32*1024 KV partials
#define WS_KSP   721920    // 2*8*32*32 Ksum partials
#define WS_KV    738304    // 2*8*1024
#define WS_KSUM  754688    // 2*8*32

// ---------------- W_fused = mheads1_w (512x256) @ q_w (256x256) ----------------
__global__ __launch_bounds__(256) void k_wfuse(const float* __restrict__ mh,
                                               const float* __restrict__ qw,
                                               float* __restrict__ wf) {
    __shared__ float mr[256];
    int g = blockIdx.x, t = threadIdx.x;
    mr[t] = mh[g * 256 + t];
    __syncthreads();
    float acc = 0.f;
    for (int k = 0; k < 256; k++) acc += mr[k] * qw[k * 256 + t];
    wf[g * 256 + t] = acc;
}

// ---------------- pool partials: sum of d-gathered key rows ----------------
// s[b, i*128+j, c] = 2*key[b, (2i+1)*256 + (2j+1), c]; pool = mean over 16384 rows
__global__ __launch_bounds__(256) void k_pool(const float* __restrict__ key,
                                              float* __restrict__ ppart) {
    int t = threadIdx.x;
    int blk = blockIdx.x;
    int b = blk >> 7, ci = blk & 127;  // i = ci, j = q
    float acc = 0.f;
    for (int q = 0; q < 128; q++) {
        size_t idx = ((size_t)b * 65536 + (size_t)(2 * ci + 1) * 256 + (2 * q + 1)) * 256 + t;
        acc += key[idx];
    }
    ppart[(size_t)blk * 256 + t] = acc;
}

__global__ __launch_bounds__(256) void k_pool2(const float* __restrict__ ppart,
                                               float* __restrict__ pool) {
    int b = blockIdx.x, t = threadIdx.x;
    float s = 0.f;
    for (int p = 0; p < 128; p++) s += ppart[((size_t)b * 128 + p) * 256 + t];
    pool[b * 256 + t] = s * (2.f / 16384.f);
}

// ---------------- glob = relu(pool@g1_w+g1_b)@g2_w + g2_b ----------------
__global__ __launch_bounds__(256) void k_glob(const float* __restrict__ pool,
                                              const float* __restrict__ g1w,
                                              const float* __restrict__ g1b,
                                              const float* __restrict__ g2w,
                                              const float* __restrict__ g2b,
                                              float* __restrict__ glob) {
    __shared__ float pl[256], hid[256];
    int t = threadIdx.x;
    for (int b = 0; b < BB; b++) {
        pl[t] = pool[b * 256 + t];
        __syncthreads();
        float acc = g1b[t];
        for (int k = 0; k < 256; k++) acc += pl[k] * g1w[k * 256 + t];
        hid[t] = fmaxf(acc, 0.f);
        __syncthreads();
        float a2 = g2b[t];
        for (int k = 0; k < 256; k++) a2 += hid[k] * g2w[k * 256 + t];
        glob[b * 256 + t] = a2;
        __syncthreads();
    }
}

// ---------------- generic tiled fp32 GEMM: Out = epi(A@W + bias) ----------------
// AMODE 0: A is M x KDIM row-major.  AMODE 1: A is key base, row r gathered as 2*key[d-row(r)].
// EPI 0: relu  EPI 1: fre-epilogue (sigmoid(x+glob)*high+low)  EPI 2: elu+1  EPI 3: /16384
template <int KDIM, int AMODE, int EPI>
__global__ __launch_bounds__(256) void gemm_k(const float* __restrict__ A,
                                              const float* __restrict__ W,
                                              const float* __restrict__ bias,
                                              float* __restrict__ Out,
                                              const float* __restrict__ glob,
                                              const float* __restrict__ key) {
    __shared__ __align__(16) float As[16][65];
    __shared__ __align__(16) float Ws[16][68];
    __shared__ int rowmap[64];

    const int tid = threadIdx.x;
    const int bx = blockIdx.x & 3;
    const int by = blockIdx.x >> 2;
    const int r0 = by * 64;
    const int n0 = bx * 64;
    const int tx = tid & 15, ty = tid >> 4;
    const int tx4 = tx * 4, ty4 = ty * 4;
    const int la_row = tid >> 2;
    const int la_k = (tid & 3) * 4;
    const int lw_k = tid >> 4;
    const int lw_n = (tid & 15) * 4;

    if constexpr (AMODE == 1) {
        if (tid < 64) {
            int r = r0 + tid;
            int b = r >> 14, rr = r & 16383;
            int i = rr >> 7, j = rr & 127;
            rowmap[tid] = b * 65536 + (2 * i + 1) * 256 + (2 * j + 1);
        }
        __syncthreads();
    }

    size_t abase;
    if constexpr (AMODE == 1)
        abase = (size_t)rowmap[la_row] * 256;
    else
        abase = (size_t)(r0 + la_row) * KDIM;

    float acc[4][4];
#pragma unroll
    for (int i = 0; i < 4; i++)
#pragma unroll
        for (int j = 0; j < 4; j++) acc[i][j] = 0.f;

    for (int k0 = 0; k0 < KDIM; k0 += 16) {
        float4 av = *(const float4*)(A + abase + k0 + la_k);
        if constexpr (AMODE == 1) { av.x *= 2.f; av.y *= 2.f; av.z *= 2.f; av.w *= 2.f; }
        float4 wv = *(const float4*)(W + (size_t)(k0 + lw_k) * 256 + n0 + lw_n);
        As[la_k + 0][la_row] = av.x;
        As[la_k + 1][la_row] = av.y;
        As[la_k + 2][la_row] = av.z;
        As[la_k + 3][la_row] = av.w;
        *(float4*)&Ws[lw_k][lw_n] = wv;
        __syncthreads();
#pragma unroll
        for (int k = 0; k < 16; k++) {
            float a0 = As[k][ty4], a1 = As[k][ty4 + 1], a2 = As[k][ty4 + 2], a3 = As[k][ty4 + 3];
            float b0 = Ws[k][tx4], b1 = Ws[k][tx4 + 1], b2 = Ws[k][tx4 + 2], b3 = Ws[k][tx4 + 3];
            acc[0][0] += a0 * b0; acc[0][1] += a0 * b1; acc[0][2] += a0 * b2; acc[0][3] += a0 * b3;
            acc[1][0] += a1 * b0; acc[1][1] += a1 * b1; acc[1][2] += a1 * b2; acc[1][3] += a1 * b3;
            acc[2][0] += a2 * b0; acc[2][1] += a2 * b1; acc[2][2] += a2 * b2; acc[2][3] += a2 * b3;
            acc[3][0] += a3 * b0; acc[3][1] += a3 * b1; acc[3][2] += a3 * b2; acc[3][3] += a3 * b3;
        }
        __syncthreads();
    }

#pragma unroll
    for (int i = 0; i < 4; i++) {
        int R = r0 + ty4 + i;
        float4 o;
        float* op = (float*)&o;
#pragma unroll
        for (int j = 0; j < 4; j++) {
            int c = n0 + tx4 + j;
            float x = acc[i][j] + bias[c];
            if constexpr (EPI == 0) {
                x = fmaxf(x, 0.f);
            } else if constexpr (EPI == 2) {
                x = (x > 0.f) ? x + 1.f : __expf(x);
            } else if constexpr (EPI == 3) {
                x = x * (1.f / 16384.f);
            } else if constexpr (EPI == 1) {
                int b = R >> 14, rr = R & 16383;
                int ii = rr >> 7, jj = rr & 127;
                size_t kb = ((size_t)b * 65536 + (size_t)(2 * ii) * 256 + 2 * jj) * 256 + c;
                float ka = key[kb];
                float kb2 = key[kb + 256];          // (2i, 2j+1)
                float kc2 = key[kb + 65536];        // (2i+1, 2j)
                float kd2 = key[kb + 65536 + 256];  // (2i+1, 2j+1)
                float low = 0.5f * (ka + kb2 + kc2 + kd2);
                float high = 0.5f * (3.f * kd2 - ka - kb2 - kc2);
                float xg = x + glob[b * 256 + c];
                float wei = 1.f / (1.f + __expf(-xg));
                x = wei * high + low;
            }
            op[j] = x;
        }
        *(float4*)(Out + (size_t)R * 256 + n0 + tx4) = o;
    }
}

// ---------------- KV partials: per (b,h,chunk) accumulate K^T @ Vn over 512 rows ----------------
__global__ __launch_bounds__(256) void k_kv_part(const float* __restrict__ Km,
                                                 const float* __restrict__ Vn,
                                                 float* __restrict__ kvp,
                                                 float* __restrict__ ksp) {
    __shared__ float Kl[8][33];
    __shared__ float Vl[8][33];
    int t = threadIdx.x;
    int c = blockIdx.x & 31, h = (blockIdx.x >> 5) & 7, b = blockIdx.x >> 8;
    int d = t >> 3, vq = (t & 7) * 4;
    int lr = t >> 5, lc = t & 31;
    float acc0 = 0, acc1 = 0, acc2 = 0, acc3 = 0, ks = 0;
    size_t rowbase = (size_t)b * 16384 + (size_t)c * 512;
    for (int s0 = 0; s0 < 512; s0 += 8) {
        size_t idx = (rowbase + s0 + lr) * 256 + h * 32 + lc;
        Kl[lr][lc] = Km[idx];
        Vl[lr][lc] = Vn[idx];
        __syncthreads();
#pragma unroll
        for (int rr = 0; rr < 8; rr++) {
            float kd = Kl[rr][d];
            acc0 += kd * Vl[rr][vq];
            acc1 += kd * Vl[rr][vq + 1];
            acc2 += kd * Vl[rr][vq + 2];
            acc3 += kd * Vl[rr][vq + 3];
            ks += kd;
        }
        __syncthreads();
    }
    size_t ob = ((size_t)(b * 8 + h) * 32 + c) * 1024 + d * 32 + vq;
    kvp[ob] = acc0; kvp[ob + 1] = acc1; kvp[ob + 2] = acc2; kvp[ob + 3] = acc3;
    if ((t & 7) == 0) ksp[((b * 8 + h) * 32 + c) * 32 + d] = ks;
}

__global__ __launch_bounds__(256) void k_kv_reduce(const float* __restrict__ kvp,
                                                   const float* __restrict__ ksp,
                                                   float* __restrict__ KV,
                                                   float* __restrict__ Ks) {
    int bh = blockIdx.x, t = threadIdx.x;
    for (int e = t; e < 1024; e += 256) {
        float s = 0.f;
        for (int cc = 0; cc < 32; cc++) s += kvp[((size_t)bh * 32 + cc) * 1024 + e];
        KV[bh * 1024 + e] = s;
    }
    if (t < 32) {
        float s = 0.f;
        for (int cc = 0; cc < 32; cc++) s += ksp[(bh * 32 + cc) * 32 + t];
        Ks[bh * 32 + t] = s;
    }
}

// ---------------- fused Q-GEMM (K=512) + linear-attention epilogue ----------------
__global__ __launch_bounds__(256) void k_qattn(const float* __restrict__ query,
                                               const float* __restrict__ Wf,
                                               const float* __restrict__ qb,
                                               const float* __restrict__ KV,
                                               const float* __restrict__ Ksum,
                                               float* __restrict__ Out) {
    __shared__ __align__(16) float As[16][65];
    __shared__ __align__(16) float Ws[16][68];
    __shared__ float Qs[64][65];
    __shared__ float KVs[2048];
    __shared__ float Ks[64];

    const int tid = threadIdx.x;
    const int bx = blockIdx.x & 3;
    const int by = blockIdx.x >> 2;
    const int r0 = by * 64;
    const int n0 = bx * 64;
    const int tx = tid & 15, ty = tid >> 4;
    const int tx4 = tx * 4, ty4 = ty * 4;
    const int la_row = tid >> 2;
    const int la_k = (tid & 3) * 4;
    const int lw_k = tid >> 4;
    const int lw_n = (tid & 15) * 4;

    const int b = r0 >> 16;
    const int h0 = 2 * bx;
    for (int e = tid; e < 2048; e += 256) KVs[e] = KV[(size_t)(b * 8 + h0) * 1024 + e];
    if (tid < 64) Ks[tid] = Ksum[(b * 8 + h0) * 32 + tid];

    size_t abase = (size_t)(r0 + la_row) * 512;
    float acc[4][4];
#pragma unroll
    for (int i = 0; i < 4; i++)
#pragma unroll
        for (int j = 0; j < 4; j++) acc[i][j] = 0.f;

    for (int k0 = 0; k0 < 512; k0 += 16) {
        float4 av = *(const float4*)(query + abase + k0 + la_k);
        float4 wv = *(const float4*)(Wf + (size_t)(k0 + lw_k) * 256 + n0 + lw_n);
        As[la_k + 0][la_row] = av.x;
        As[la_k + 1][la_row] = av.y;
        As[la_k + 2][la_row] = av.z;
        As[la_k + 3][la_row] = av.w;
        *(float4*)&Ws[lw_k][lw_n] = wv;
        __syncthreads();
#pragma unroll
        for (int k = 0; k < 16; k++) {
            float a0 = As[k][ty4], a1 = As[k][ty4 + 1], a2 = As[k][ty4 + 2], a3 = As[k][ty4 + 3];
            float b0 = Ws[k][tx4], b1 = Ws[k][tx4 + 1], b2 = Ws[k][tx4 + 2], b3 = Ws[k][tx4 + 3];
            acc[0][0] += a0 * b0; acc[0][1] += a0 * b1; acc[0][2] += a0 * b2; acc[0][3] += a0 * b3;
            acc[1][0] += a1 * b0; acc[1][1] += a1 * b1; acc[1][2] += a1 * b2; acc[1][3] += a1 * b3;
            acc[2][0] += a2 * b0; acc[2][1] += a2 * b1; acc[2][2] += a2 * b2; acc[2][3] += a2 * b3;
            acc[3][0] += a3 * b0; acc[3][1] += a3 * b1; acc[3][2] += a3 * b2; acc[3][3] += a3 * b3;
        }
        __syncthreads();
    }

    // Q = elu(qh)+1 into LDS
#pragma unroll
    for (int i = 0; i < 4; i++) {
#pragma unroll
        for (int j = 0; j < 4; j++) {
            int c = n0 + tx4 + j;
            float x = acc[i][j] + qb[c];
            Qs[ty4 + i][tx4 + j] = (x > 0.f) ? x + 1.f : __expf(x);
        }
    }
    __syncthreads();

    const int hh = tx >> 3;  // local head (0 or 1)
    const float* kvh = &KVs[hh * 1024];
    const float* ksh = &Ks[hh * 32];
#pragma unroll
    for (int i = 0; i < 4; i++) {
        int r = ty4 + i;
        float z = 0.f;
#pragma unroll
        for (int d = 0; d < 32; d++) z += Qs[r][hh * 32 + d] * ksh[d];
        float zi = 16384.f / (z + 1e-6f);
        float4 o;
        float* op = (float*)&o;
#pragma unroll
        for (int j = 0; j < 4; j++) {
            int v = (tx4 + j) & 31;
            float s = 0.f;
#pragma unroll
            for (int d = 0; d < 32; d++) s += Qs[r][hh * 32 + d] * kvh[d * 32 + v];
            op[j] = s * zi;
        }
        *(float4*)(Out + (size_t)(r0 + r) * 256 + n0 + tx4) = o;
    }
}

extern "C" void kernel_launch(void* const* d_in, const int* in_sizes, int n_in,
                              void* d_out, int out_size, void* d_ws, size_t ws_size,
                              hipStream_t stream) {
    const float* query = (const float*)d_in[0];
    const float* key = (const float*)d_in[1];
    // d_in[2] = value: only its shape is used by the reference — never read.
    const float* mh = (const float*)d_in[3];
    const float* q_w = (const float*)d_in[4];
    const float* q_b = (const float*)d_in[5];
    const float* k_w = (const float*)d_in[6];
    const float* k_b = (const float*)d_in[7];
    const float* v_w = (const float*)d_in[8];
    const float* v_b = (const float*)d_in[9];
    const float* l1_w = (const float*)d_in[10];
    const float* l1_b = (const float*)d_in[11];
    const float* l2_w = (const float*)d_in[12];
    const float* l2_b = (const float*)d_in[13];
    const float* g1_w = (const float*)d_in[14];
    const float* g1_b = (const float*)d_in[15];
    const float* g2_w = (const float*)d_in[16];
    const float* g2_b = (const float*)d_in[17];

    float* out = (float*)d_out;
    float* ws = (float*)d_ws;

    float* wf = ws + WS_WF;
    float* ppart = ws + WS_PPART;
    float* pool = ws + WS_POOL;
    float* glob = ws + WS_GLOB;
    float* kvp = ws + WS_KVP;
    float* ksp = ws + WS_KSP;
    float* KV = ws + WS_KV;
    float* Ksum = ws + WS_KSUM;

    // big intermediates live inside d_out (final kernel overwrites everything)
    float* t = out;               // 32768 x 256
    float* fre = out + 8388608;   // 32768 x 256
    float* Km = out + 16777216;   // 32768 x 256
    float* Vn = out + 25165824;   // 32768 x 256

    k_wfuse<<<512, 256, 0, stream>>>(mh, q_w, wf);
    k_pool<<<256, 256, 0, stream>>>(key, ppart);
    k_pool2<<<2, 256, 0, stream>>>(ppart, pool);
    k_glob<<<1, 256, 0, stream>>>(pool, g1_w, g1_b, g2_w, g2_b, glob);

    // t = relu(s @ l1_w + l1_b), s gathered from key
    gemm_k<256, 1, 0><<<2048, 256, 0, stream>>>(key, l1_w, l1_b, t, nullptr, nullptr);
    // fre = sigmoid(t @ l2_w + l2_b + glob) * high + low
    gemm_k<256, 0, 1><<<2048, 256, 0, stream>>>(t, l2_w, l2_b, fre, glob, key);
    // K = elu(fre @ k_w + k_b) + 1
    gemm_k<256, 0, 2><<<2048, 256, 0, stream>>>(fre, k_w, k_b, Km, nullptr, nullptr);
    // Vn = (fre @ v_w + v_b) / 16384
    gemm_k<256, 0, 3><<<2048, 256, 0, stream>>>(fre, v_w, v_b, Vn, nullptr, nullptr);

    k_kv_part<<<512, 256, 0, stream>>>(Km, Vn, kvp, ksp);
    k_kv_reduce<<<16, 256, 0, stream>>>(kvp, ksp, KV, Ksum);

    // out = (elu(query @ Wf + q_b)+1) attention epilogue
    k_qattn<<<8192, 256, 0, stream>>>(query, wf, q_b, KV, Ksum, out);
}

// Round 2
// 502.867 us; speedup vs baseline: 3.4318x; 3.4318x over previous
//
#include <hip/hip_runtime.h>
#include <math.h>

// Problem constants
#define BB 2
#define N1 65536
#define N2 16384
#define CC 256
#define GG 512
#define NH 8
#define DH 32

// ws layout (float offsets)
#define WS_PPART 131072    // 2*128*256 pool partials
#define WS_POOL  196608    // 2*256
#define WS_GLOB  197120    // 2*256
#define WS_KVP   197632    // 2*8*32*1024 KV partials
#define WS_KSP   721920    // 2*8*32*32 Ksum partials
#define WS_KVT   755200    // bf16 KV_aug: 16*48*32 ushort = 12288 floats
#define WS_WFT   767488    // bf16 Wf^T: 256*512 ushort = 65536 floats

typedef __attribute__((ext_vector_type(8))) short short8v;
typedef __attribute__((ext_vector_type(4))) float f32x4;

__device__ __forceinline__ ushort f2bf(float x) {
    union { float f; unsigned int u; } v; v.f = x;
    unsigned int u = v.u;
    unsigned int r = (u + 0x7fffu + ((u >> 16) & 1u)) >> 16;
    return (ushort)r;
}

// ---------------- Wf^T (bf16) = (mheads1_w (512x256) @ q_w (256x256))^T ----------------
__global__ __launch_bounds__(256) void k_wfuse(const float* __restrict__ mh,
                                               const float* __restrict__ qw,
                                               ushort* __restrict__ wft) {
    __shared__ float mr[256];
    int g = blockIdx.x, t = threadIdx.x;
    mr[t] = mh[g * 256 + t];
    __syncthreads();
    float acc = 0.f;
    for (int k = 0; k < 256; k++) acc += mr[k] * qw[k * 256 + t];
    wft[(size_t)t * 512 + g] = f2bf(acc);   // layout [n][k], pitch 512
}

// ---------------- pool partials ----------------
__global__ __launch_bounds__(256) void k_pool(const float* __restrict__ key,
                                              float* __restrict__ ppart) {
    int t = threadIdx.x;
    int blk = blockIdx.x;
    int b = blk >> 7, ci = blk & 127;
    float acc = 0.f;
    for (int q = 0; q < 128; q++) {
        size_t idx = ((size_t)b * 65536 + (size_t)(2 * ci + 1) * 256 + (2 * q + 1)) * 256 + t;
        acc += key[idx];
    }
    ppart[(size_t)blk * 256 + t] = acc;
}

__global__ __launch_bounds__(256) void k_pool2(const float* __restrict__ ppart,
                                               float* __restrict__ pool) {
    int b = blockIdx.x, t = threadIdx.x;
    float s = 0.f;
    for (int p = 0; p < 128; p++) s += ppart[((size_t)b * 128 + p) * 256 + t];
    pool[b * 256 + t] = s * (2.f / 16384.f);
}

// ---------------- glob ----------------
__global__ __launch_bounds__(256) void k_glob(const float* __restrict__ pool,
                                              const float* __restrict__ g1w,
                                              const float* __restrict__ g1b,
                                              const float* __restrict__ g2w,
                                              const float* __restrict__ g2b,
                                              float* __restrict__ glob) {
    __shared__ float pl[256], hid[256];
    int t = threadIdx.x;
    for (int b = 0; b < BB; b++) {
        pl[t] = pool[b * 256 + t];
        __syncthreads();
        float acc = g1b[t];
        for (int k = 0; k < 256; k++) acc += pl[k] * g1w[k * 256 + t];
        hid[t] = fmaxf(acc, 0.f);
        __syncthreads();
        float a2 = g2b[t];
        for (int k = 0; k < 256; k++) a2 += hid[k] * g2w[k * 256 + t];
        glob[b * 256 + t] = a2;
        __syncthreads();
    }
}

// ---------------- generic tiled fp32 GEMM (mid-size, unchanged this round) ----------------
template <int KDIM, int AMODE, int EPI>
__global__ __launch_bounds__(256) void gemm_k(const float* __restrict__ A,
                                              const float* __restrict__ W,
                                              const float* __restrict__ bias,
                                              float* __restrict__ Out,
                                              const float* __restrict__ glob,
                                              const float* __restrict__ key) {
    __shared__ __align__(16) float As[16][65];
    __shared__ __align__(16) float Ws[16][68];
    __shared__ int rowmap[64];

    const int tid = threadIdx.x;
    const int bx = blockIdx.x & 3;
    const int by = blockIdx.x >> 2;
    const int r0 = by * 64;
    const int n0 = bx * 64;
    const int tx = tid & 15, ty = tid >> 4;
    const int tx4 = tx * 4, ty4 = ty * 4;
    const int la_row = tid >> 2;
    const int la_k = (tid & 3) * 4;
    const int lw_k = tid >> 4;
    const int lw_n = (tid & 15) * 4;

    if constexpr (AMODE == 1) {
        if (tid < 64) {
            int r = r0 + tid;
            int b = r >> 14, rr = r & 16383;
            int i = rr >> 7, j = rr & 127;
            rowmap[tid] = b * 65536 + (2 * i + 1) * 256 + (2 * j + 1);
        }
        __syncthreads();
    }

    size_t abase;
    if constexpr (AMODE == 1)
        abase = (size_t)rowmap[la_row] * 256;
    else
        abase = (size_t)(r0 + la_row) * KDIM;

    float acc[4][4];
#pragma unroll
    for (int i = 0; i < 4; i++)
#pragma unroll
        for (int j = 0; j < 4; j++) acc[i][j] = 0.f;

    for (int k0 = 0; k0 < KDIM; k0 += 16) {
        float4 av = *(const float4*)(A + abase + k0 + la_k);
        if constexpr (AMODE == 1) { av.x *= 2.f; av.y *= 2.f; av.z *= 2.f; av.w *= 2.f; }
        float4 wv = *(const float4*)(W + (size_t)(k0 + lw_k) * 256 + n0 + lw_n);
        As[la_k + 0][la_row] = av.x;
        As[la_k + 1][la_row] = av.y;
        As[la_k + 2][la_row] = av.z;
        As[la_k + 3][la_row] = av.w;
        *(float4*)&Ws[lw_k][lw_n] = wv;
        __syncthreads();
#pragma unroll
        for (int k = 0; k < 16; k++) {
            float a0 = As[k][ty4], a1 = As[k][ty4 + 1], a2 = As[k][ty4 + 2], a3 = As[k][ty4 + 3];
            float b0 = Ws[k][tx4], b1 = Ws[k][tx4 + 1], b2 = Ws[k][tx4 + 2], b3 = Ws[k][tx4 + 3];
            acc[0][0] += a0 * b0; acc[0][1] += a0 * b1; acc[0][2] += a0 * b2; acc[0][3] += a0 * b3;
            acc[1][0] += a1 * b0; acc[1][1] += a1 * b1; acc[1][2] += a1 * b2; acc[1][3] += a1 * b3;
            acc[2][0] += a2 * b0; acc[2][1] += a2 * b1; acc[2][2] += a2 * b2; acc[2][3] += a2 * b3;
            acc[3][0] += a3 * b0; acc[3][1] += a3 * b1; acc[3][2] += a3 * b2; acc[3][3] += a3 * b3;
        }
        __syncthreads();
    }

#pragma unroll
    for (int i = 0; i < 4; i++) {
        int R = r0 + ty4 + i;
        float4 o;
        float* op = (float*)&o;
#pragma unroll
        for (int j = 0; j < 4; j++) {
            int c = n0 + tx4 + j;
            float x = acc[i][j] + bias[c];
            if constexpr (EPI == 0) {
                x = fmaxf(x, 0.f);
            } else if constexpr (EPI == 2) {
                x = (x > 0.f) ? x + 1.f : __expf(x);
            } else if constexpr (EPI == 3) {
                x = x * (1.f / 16384.f);
            } else if constexpr (EPI == 1) {
                int b = R >> 14, rr = R & 16383;
                int ii = rr >> 7, jj = rr & 127;
                size_t kb = ((size_t)b * 65536 + (size_t)(2 * ii) * 256 + 2 * jj) * 256 + c;
                float ka = key[kb];
                float kb2 = key[kb + 256];
                float kc2 = key[kb + 65536];
                float kd2 = key[kb + 65536 + 256];
                float low = 0.5f * (ka + kb2 + kc2 + kd2);
                float high = 0.5f * (3.f * kd2 - ka - kb2 - kc2);
                float xg = x + glob[b * 256 + c];
                float wei = 1.f / (1.f + __expf(-xg));
                x = wei * high + low;
            }
            op[j] = x;
        }
        *(float4*)(Out + (size_t)R * 256 + n0 + tx4) = o;
    }
}

// ---------------- KV partials ----------------
__global__ __launch_bounds__(256) void k_kv_part(const float* __restrict__ Km,
                                                 const float* __restrict__ Vn,
                                                 float* __restrict__ kvp,
                                                 float* __restrict__ ksp) {
    __shared__ float Kl[8][33];
    __shared__ float Vl[8][33];
    int t = threadIdx.x;
    int c = blockIdx.x & 31, h = (blockIdx.x >> 5) & 7, b = blockIdx.x >> 8;
    int d = t >> 3, vq = (t & 7) * 4;
    int lr = t >> 5, lc = t & 31;
    float acc0 = 0, acc1 = 0, acc2 = 0, acc3 = 0, ks = 0;
    size_t rowbase = (size_t)b * 16384 + (size_t)c * 512;
    for (int s0 = 0; s0 < 512; s0 += 8) {
        size_t idx = (rowbase + s0 + lr) * 256 + h * 32 + lc;
        Kl[lr][lc] = Km[idx];
        Vl[lr][lc] = Vn[idx];
        __syncthreads();
#pragma unroll
        for (int rr = 0; rr < 8; rr++) {
            float kd = Kl[rr][d];
            acc0 += kd * Vl[rr][vq];
            acc1 += kd * Vl[rr][vq + 1];
            acc2 += kd * Vl[rr][vq + 2];
            acc3 += kd * Vl[rr][vq + 3];
            ks += kd;
        }
        __syncthreads();
    }
    size_t ob = ((size_t)(b * 8 + h) * 32 + c) * 1024 + d * 32 + vq;
    kvp[ob] = acc0; kvp[ob + 1] = acc1; kvp[ob + 2] = acc2; kvp[ob + 3] = acc3;
    if ((t & 7) == 0) ksp[((b * 8 + h) * 32 + c) * 32 + d] = ks;
}

// ---------------- KV reduce -> bf16 augmented B^T: KVt[bh][48][32] ----------------
// rows 0..31: KVt[v][d] = KV[d][v]; row 32: Ksum[d]; rows 33..47: 0
__global__ __launch_bounds__(256) void k_kv_reduce(const float* __restrict__ kvp,
                                                   const float* __restrict__ ksp,
                                                   ushort* __restrict__ kvt) {
    int bh = blockIdx.x, t = threadIdx.x;
    for (int e = t; e < 1024; e += 256) {
        float s = 0.f;
        for (int cc = 0; cc < 32; cc++) s += kvp[((size_t)bh * 32 + cc) * 1024 + e];
        int d = e >> 5, v = e & 31;
        kvt[((size_t)bh * 48 + v) * 32 + d] = f2bf(s);
    }
    if (t < 32) {
        float s = 0.f;
        for (int cc = 0; cc < 32; cc++) s += ksp[(bh * 32 + cc) * 32 + t];
        kvt[((size_t)bh * 48 + 32) * 32 + t] = f2bf(s);
    }
    for (int z = t; z < 480; z += 256) kvt[(size_t)bh * 48 * 32 + 33 * 32 + z] = 0;
}

// ---------------- MFMA q-GEMM (M=131072, K=512, N=256) + linear-attn epilogue ----------------
// 128x128 tile, 4 waves (2x2), each wave 64x64 via 4x4 frags of 16x16x32 bf16.
__global__ __launch_bounds__(256) void k_qattn_mfma(const float* __restrict__ query,
                                                    const ushort* __restrict__ wft,
                                                    const float* __restrict__ qb,
                                                    const ushort* __restrict__ kvt,
                                                    float* __restrict__ Out) {
    // As: [128][32] bf16 (8KB) | Bs: [128][32] bf16 (8KB); Qs overlays all 32KB after main loop
    __shared__ __align__(16) ushort smem[16384];
    ushort* As = smem;
    ushort* Bs = smem + 4096;

    const int tid = threadIdx.x;
    const int lane = tid & 63;
    const int wid = tid >> 6;
    const int wrow = wid >> 1, wcol = wid & 1;
    const int bx = blockIdx.x & 1;
    const int by = blockIdx.x >> 1;
    const int r0 = by * 128;
    const int n0 = bx * 128;
    const int l15 = lane & 15, l4 = lane >> 4;

    const int srow = tid >> 1;   // staging row 0..127
    const int shalf = tid & 1;   // 16-float half
    const size_t agbase = (size_t)(r0 + srow) * 512 + shalf * 16;

    f32x4 acc[4][4];
#pragma unroll
    for (int i = 0; i < 4; i++)
#pragma unroll
        for (int j = 0; j < 4; j++) acc[i][j] = (f32x4){0.f, 0.f, 0.f, 0.f};

    for (int ks = 0; ks < 16; ks++) {
        // stage B (bf16 copy, [n][k] -> linear [128][32])
#pragma unroll
        for (int j = 0; j < 2; j++) {
            int c = tid * 2 + j;
            uint4 wv = *(const uint4*)(wft + (size_t)(n0 + (c >> 2)) * 512 + ks * 32 + (c & 3) * 8);
            *(uint4*)((char*)Bs + c * 16) = wv;
        }
        // stage A (fp32 -> bf16)
        {
            float f[16];
#pragma unroll
            for (int i = 0; i < 4; i++) {
                float4 t4 = *(const float4*)(query + agbase + (size_t)ks * 32 + i * 4);
                f[i * 4 + 0] = t4.x; f[i * 4 + 1] = t4.y; f[i * 4 + 2] = t4.z; f[i * 4 + 3] = t4.w;
            }
            unsigned int w[8];
#pragma unroll
            for (int i = 0; i < 8; i++)
                w[i] = (unsigned int)f2bf(f[2 * i]) | ((unsigned int)f2bf(f[2 * i + 1]) << 16);
            uint4 lo = {w[0], w[1], w[2], w[3]}, hi = {w[4], w[5], w[6], w[7]};
            *(uint4*)((char*)As + srow * 64 + shalf * 32) = lo;
            *(uint4*)((char*)As + srow * 64 + shalf * 32 + 16) = hi;
        }
        __syncthreads();

        short8v a[4], bfr[4];
#pragma unroll
        for (int m = 0; m < 4; m++)
            a[m] = *(const short8v*)((const char*)As + (wrow * 64 + m * 16 + l15) * 64 + l4 * 16);
#pragma unroll
        for (int n = 0; n < 4; n++)
            bfr[n] = *(const short8v*)((const char*)Bs + (wcol * 64 + n * 16 + l15) * 64 + l4 * 16);
#pragma unroll
        for (int m = 0; m < 4; m++)
#pragma unroll
            for (int n = 0; n < 4; n++)
                acc[m][n] = __builtin_amdgcn_mfma_f32_16x16x32_bf16(a[m], bfr[n], acc[m][n], 0, 0, 0);
        __syncthreads();
    }

    // Q = elu(x+qb)+1 -> Qs bf16 [128][128], XOR-swizzled (byte ^= (row&7)<<4)
    float qbv[4];
#pragma unroll
    for (int n = 0; n < 4; n++) qbv[n] = qb[n0 + wcol * 64 + n * 16 + l15];
#pragma unroll
    for (int m = 0; m < 4; m++) {
#pragma unroll
        for (int n = 0; n < 4; n++) {
#pragma unroll
            for (int r = 0; r < 4; r++) {
                int rl = wrow * 64 + m * 16 + l4 * 4 + r;
                int cl = wcol * 64 + n * 16 + l15;
                float x = acc[m][n][r] + qbv[n];
                float q = x > 0.f ? x + 1.f : __expf(x);
                int byte = (rl * 256 + cl * 2) ^ ((rl & 7) << 4);
                *(ushort*)((char*)smem + byte) = f2bf(q);
            }
        }
    }
    __syncthreads();

    // attention epilogue: per head O = Q_h @ KV_aug (48 cols: 32 KV, col32 = Ksum)
    const int bb = r0 >> 16;
#pragma unroll
    for (int hi = 0; hi < 2; hi++) {
        int h = bx * 4 + wcol * 2 + hi;
        int bh = bb * 8 + h;
        const ushort* kb = kvt + (size_t)bh * 48 * 32;
        short8v bk0 = *(const short8v*)(kb + (0 * 16 + l15) * 32 + l4 * 8);
        short8v bk1 = *(const short8v*)(kb + (1 * 16 + l15) * 32 + l4 * 8);
        short8v bkz = *(const short8v*)(kb + (2 * 16 + l15) * 32 + l4 * 8);
#pragma unroll
        for (int m = 0; m < 4; m++) {
            int rl = wrow * 64 + m * 16 + l15;
            int byte = (rl * 256 + wcol * 128 + hi * 64 + l4 * 16) ^ ((rl & 7) << 4);
            short8v aq = *(const short8v*)((const char*)smem + byte);
            f32x4 zero = (f32x4){0.f, 0.f, 0.f, 0.f};
            f32x4 o0 = __builtin_amdgcn_mfma_f32_16x16x32_bf16(aq, bk0, zero, 0, 0, 0);
            f32x4 o1 = __builtin_amdgcn_mfma_f32_16x16x32_bf16(aq, bk1, zero, 0, 0, 0);
            f32x4 oz = __builtin_amdgcn_mfma_f32_16x16x32_bf16(aq, bkz, zero, 0, 0, 0);
#pragma unroll
            for (int r = 0; r < 4; r++) {
                float z = __shfl(oz[r], (lane & 48));
                float sc = 16384.f / (z + 1e-6f);
                int grow = r0 + wrow * 64 + m * 16 + l4 * 4 + r;
                int gcol = n0 + wcol * 64 + hi * 32 + l15;
                Out[(size_t)grow * 256 + gcol] = o0[r] * sc;
                Out[(size_t)grow * 256 + gcol + 16] = o1[r] * sc;
            }
        }
    }
}

extern "C" void kernel_launch(void* const* d_in, const int* in_sizes, int n_in,
                              void* d_out, int out_size, void* d_ws, size_t ws_size,
                              hipStream_t stream) {
    const float* query = (const float*)d_in[0];
    const float* key = (const float*)d_in[1];
    // d_in[2] = value: only its shape is used by the reference — never read.
    const float* mh = (const float*)d_in[3];
    const float* q_w = (const float*)d_in[4];
    const float* q_b = (const float*)d_in[5];
    const float* k_w = (const float*)d_in[6];
    const float* k_b = (const float*)d_in[7];
    const float* v_w = (const float*)d_in[8];
    const float* v_b = (const float*)d_in[9];
    const float* l1_w = (const float*)d_in[10];
    const float* l1_b = (const float*)d_in[11];
    const float* l2_w = (const float*)d_in[12];
    const float* l2_b = (const float*)d_in[13];
    const float* g1_w = (const float*)d_in[14];
    const float* g1_b = (const float*)d_in[15];
    const float* g2_w = (const float*)d_in[16];
    const float* g2_b = (const float*)d_in[17];

    float* out = (float*)d_out;
    float* ws = (float*)d_ws;

    float* ppart = ws + WS_PPART;
    float* pool = ws + WS_POOL;
    float* glob = ws + WS_GLOB;
    float* kvp = ws + WS_KVP;
    float* ksp = ws + WS_KSP;
    ushort* kvt = (ushort*)(ws + WS_KVT);
    ushort* wft = (ushort*)(ws + WS_WFT);

    // big intermediates live inside d_out (final kernel overwrites everything)
    float* t = out;               // 32768 x 256
    float* fre = out + 8388608;   // 32768 x 256
    float* Km = out + 16777216;   // 32768 x 256
    float* Vn = out + 25165824;   // 32768 x 256

    k_wfuse<<<512, 256, 0, stream>>>(mh, q_w, wft);
    k_pool<<<256, 256, 0, stream>>>(key, ppart);
    k_pool2<<<2, 256, 0, stream>>>(ppart, pool);
    k_glob<<<1, 256, 0, stream>>>(pool, g1_w, g1_b, g2_w, g2_b, glob);

    gemm_k<256, 1, 0><<<2048, 256, 0, stream>>>(key, l1_w, l1_b, t, nullptr, nullptr);
    gemm_k<256, 0, 1><<<2048, 256, 0, stream>>>(t, l2_w, l2_b, fre, glob, key);
    gemm_k<256, 0, 2><<<2048, 256, 0, stream>>>(fre, k_w, k_b, Km, nullptr, nullptr);
    gemm_k<256, 0, 3><<<2048, 256, 0, stream>>>(fre, v_w, v_b, Vn, nullptr, nullptr);

    k_kv_part<<<512, 256, 0, stream>>>(Km, Vn, kvp, ksp);
    k_kv_reduce<<<16, 256, 0, stream>>>(kvp, ksp, kvt);

    k_qattn_mfma<<<2048, 256, 0, stream>>>(query, wft, q_b, kvt, out);
}

// Round 3
// 322.196 us; speedup vs baseline: 5.3562x; 1.5607x over previous
//
#include <hip/hip_runtime.h>
#include <math.h>

// Problem constants
#define BB 2
#define N1 65536
#define N2 16384
#define CC 256
#define GG 512
#define NH 8
#define DH 32

// ws layout (float offsets)
#define WS_PPART 0         // 2*128*256 pool partials
#define WS_POOL  65536     // 2*256
#define WS_GLOB  66048     // 2*256
#define WS_KVP   66560     // 2*8*32*1024 KV partials
#define WS_KSP   590848    // 2*8*32*32 Ksum partials
#define WS_KVT   607232    // bf16 KV_aug: 16*48*32 ushort = 12288 floats
#define WS_WFP   619520    // bf16 Wf pre-tiled: 2*16*128*32 ushort = 65536 floats
#define WS_L1T   685056    // bf16 l1 pre-tiled: 2*8*128*32 ushort = 32768 floats
#define WS_L2T   717824
#define WS_KWT   750592
#define WS_VWT   783360

typedef __attribute__((ext_vector_type(8))) short short8v;
typedef __attribute__((ext_vector_type(4))) float f32x4;

__device__ __forceinline__ ushort f2bf(float x) {
    union { float f; unsigned int u; } v; v.f = x;
    unsigned int u = v.u;
    unsigned int r = (u + 0x7fffu + ((u >> 16) & 1u)) >> 16;
    return (ushort)r;
}

// async global->LDS, 16B per lane; lds base must be wave-uniform
__device__ __forceinline__ void gload16(const void* g, void* l) {
    __builtin_amdgcn_global_load_lds(
        (const __attribute__((address_space(1))) unsigned int*)g,
        (__attribute__((address_space(3))) unsigned int*)l, 16, 0, 0);
}

// ---------------- pre-tile 4 weight matrices (256x256, [k][n]) to bf16 panels ----------------
// tile[(n>>7)][(k>>5)][n&127][k&31]
__global__ __launch_bounds__(256) void k_wprep(const float* __restrict__ w0, const float* __restrict__ w1,
                                               const float* __restrict__ w2, const float* __restrict__ w3,
                                               ushort* __restrict__ t0, ushort* __restrict__ t1,
                                               ushort* __restrict__ t2, ushort* __restrict__ t3) {
    int blk = blockIdx.x;
    int mat = blk >> 8, k = blk & 255, n = threadIdx.x;
    const float* w = mat == 0 ? w0 : mat == 1 ? w1 : mat == 2 ? w2 : w3;
    ushort* o = mat == 0 ? t0 : mat == 1 ? t1 : mat == 2 ? t2 : t3;
    o[(((size_t)(n >> 7) * 8 + (k >> 5)) * 128 + (n & 127)) * 32 + (k & 31)] = f2bf(w[k * 256 + n]);
}

// ---------------- Wf pre-tiled bf16 = (mheads1_w (512x256) @ q_w (256x256)), [bx][ks][128][32] ----------------
__global__ __launch_bounds__(256) void k_wfuse(const float* __restrict__ mh,
                                               const float* __restrict__ qw,
                                               ushort* __restrict__ wfp) {
    __shared__ float mr[256];
    int g = blockIdx.x, t = threadIdx.x;   // g = k index (0..511), t = n (0..255)
    mr[t] = mh[g * 256 + t];
    __syncthreads();
    float acc = 0.f;
    for (int k = 0; k < 256; k++) acc += mr[k] * qw[k * 256 + t];
    wfp[(((size_t)(t >> 7) * 16 + (g >> 5)) * 128 + (t & 127)) * 32 + (g & 31)] = f2bf(acc);
}

// ---------------- pool partials ----------------
__global__ __launch_bounds__(256) void k_pool(const float* __restrict__ key,
                                              float* __restrict__ ppart) {
    int t = threadIdx.x;
    int blk = blockIdx.x;
    int b = blk >> 7, ci = blk & 127;
    float acc = 0.f;
    for (int q = 0; q < 128; q++) {
        size_t idx = ((size_t)b * 65536 + (size_t)(2 * ci + 1) * 256 + (2 * q + 1)) * 256 + t;
        acc += key[idx];
    }
    ppart[(size_t)blk * 256 + t] = acc;
}

__global__ __launch_bounds__(256) void k_pool2(const float* __restrict__ ppart,
                                               float* __restrict__ pool) {
    int b = blockIdx.x, t = threadIdx.x;
    float s = 0.f;
    for (int p = 0; p < 128; p++) s += ppart[((size_t)b * 128 + p) * 256 + t];
    pool[b * 256 + t] = s * (2.f / 16384.f);
}

// ---------------- glob ----------------
__global__ __launch_bounds__(256) void k_glob(const float* __restrict__ pool,
                                              const float* __restrict__ g1w,
                                              const float* __restrict__ g1b,
                                              const float* __restrict__ g2w,
                                              const float* __restrict__ g2b,
                                              float* __restrict__ glob) {
    __shared__ float pl[256], hid[256];
    int t = threadIdx.x;
    for (int b = 0; b < BB; b++) {
        pl[t] = pool[b * 256 + t];
        __syncthreads();
        float acc = g1b[t];
        for (int k = 0; k < 256; k++) acc += pl[k] * g1w[k * 256 + t];
        hid[t] = fmaxf(acc, 0.f);
        __syncthreads();
        float a2 = g2b[t];
        for (int k = 0; k < 256; k++) a2 += hid[k] * g2w[k * 256 + t];
        glob[b * 256 + t] = a2;
        __syncthreads();
    }
}

// ---------------- bf16 MFMA mid GEMM: 128x128 tile, K=256, M=32768 ----------------
// AMODE 0: A = bf16 rows [m][256].  AMODE 1: A gathered from key (fp32, x2, -> bf16).
// EPI 0: relu -> bf16   EPI 1: fre epilogue -> bf16   EPI 2: elu+1 -> f32   EPI 3: identity -> f32
template <int AMODE, int EPI>
__global__ __launch_bounds__(256) void gemm_bf(const void* __restrict__ Asrc_,
                                               const ushort* __restrict__ Wt,
                                               const float* __restrict__ bias,
                                               void* __restrict__ Outp,
                                               const float* __restrict__ glob,
                                               const float* __restrict__ key) {
    __shared__ __align__(16) ushort smem[8192];   // As 8KB | Bs 8KB
    ushort* As = smem;
    ushort* Bs = smem + 4096;

    const int tid = threadIdx.x;
    const int lane = tid & 63;
    const int w = tid >> 6;
    const int wrow = w >> 1, wcol = w & 1;
    const int bx = blockIdx.x & 1;
    const int by = blockIdx.x >> 1;
    const int r0 = by * 128, n0 = bx * 128;
    const int l15 = lane & 15, l4 = lane >> 4;

    // B staging: pre-tiled contiguous 8KB per k-step
    const int loff = lane * 16;
    char* ldsB0 = (char*)Bs + w * 2048;
    char* ldsB1 = (char*)Bs + w * 2048 + 1024;
    // A staging geometry (AMODE 0, DMA)
    const int rowA0 = w * 32 + (lane >> 2);
    const int kbA = (lane & 3) * 16;
    char* ldsA0 = (char*)As + w * 2048;
    char* ldsA1 = (char*)As + w * 2048 + 1024;
    // A staging geometry (AMODE 1, reg gather)
    const int srow = tid >> 1, shalf = tid & 1;
    size_t agbase = 0;
    if constexpr (AMODE == 1) {
        int r = r0 + srow;
        int b = r >> 14, rr = r & 16383;
        int ii = rr >> 7, jj = rr & 127;
        agbase = ((size_t)b * 65536 + (size_t)(2 * ii + 1) * 256 + (2 * jj + 1)) * 256 + shalf * 16;
    }

    f32x4 acc[4][4];
#pragma unroll
    for (int i = 0; i < 4; i++)
#pragma unroll
        for (int j = 0; j < 4; j++) acc[i][j] = (f32x4){0.f, 0.f, 0.f, 0.f};

    for (int ks = 0; ks < 8; ks++) {
        const char* btile = (const char*)Wt + (size_t)(bx * 8 + ks) * 8192;
        gload16(btile + w * 2048 + loff, ldsB0);
        gload16(btile + w * 2048 + 1024 + loff, ldsB1);
        if constexpr (AMODE == 0) {
            const char* ab = (const char*)Asrc_;
            gload16(ab + (size_t)(r0 + rowA0) * 512 + ks * 64 + kbA, ldsA0);
            gload16(ab + (size_t)(r0 + rowA0 + 16) * 512 + ks * 64 + kbA, ldsA1);
        } else {
            const float* kf = (const float*)Asrc_;
            float f[16];
#pragma unroll
            for (int i = 0; i < 4; i++) {
                float4 t4 = *(const float4*)(kf + agbase + (size_t)ks * 32 + i * 4);
                f[i * 4 + 0] = t4.x * 2.f; f[i * 4 + 1] = t4.y * 2.f;
                f[i * 4 + 2] = t4.z * 2.f; f[i * 4 + 3] = t4.w * 2.f;
            }
            unsigned int wd[8];
#pragma unroll
            for (int i = 0; i < 8; i++)
                wd[i] = (unsigned int)f2bf(f[2 * i]) | ((unsigned int)f2bf(f[2 * i + 1]) << 16);
            uint4 lo = {wd[0], wd[1], wd[2], wd[3]}, hi = {wd[4], wd[5], wd[6], wd[7]};
            *(uint4*)((char*)As + srow * 64 + shalf * 32) = lo;
            *(uint4*)((char*)As + srow * 64 + shalf * 32 + 16) = hi;
        }
        __syncthreads();

        short8v a[4], bfr[4];
#pragma unroll
        for (int m = 0; m < 4; m++)
            a[m] = *(const short8v*)((const char*)As + (wrow * 64 + m * 16 + l15) * 64 + l4 * 16);
#pragma unroll
        for (int n = 0; n < 4; n++)
            bfr[n] = *(const short8v*)((const char*)Bs + (wcol * 64 + n * 16 + l15) * 64 + l4 * 16);
#pragma unroll
        for (int m = 0; m < 4; m++)
#pragma unroll
            for (int n = 0; n < 4; n++)
                acc[m][n] = __builtin_amdgcn_mfma_f32_16x16x32_bf16(a[m], bfr[n], acc[m][n], 0, 0, 0);
        __syncthreads();
    }

    // epilogue
    const int b = r0 >> 14;
    float bv[4], gv[4];
#pragma unroll
    for (int n = 0; n < 4; n++) {
        int c = n0 + wcol * 64 + n * 16 + l15;
        bv[n] = bias[c];
        if constexpr (EPI == 1) gv[n] = glob[b * 256 + c];
    }
#pragma unroll
    for (int m = 0; m < 4; m++) {
#pragma unroll
        for (int n = 0; n < 4; n++) {
            int c = n0 + wcol * 64 + n * 16 + l15;
#pragma unroll
            for (int r = 0; r < 4; r++) {
                int row = wrow * 64 + m * 16 + l4 * 4 + r;
                int R = r0 + row;
                float x = acc[m][n][r] + bv[n];
                if constexpr (EPI == 0) {
                    ((ushort*)Outp)[(size_t)R * 256 + c] = f2bf(fmaxf(x, 0.f));
                } else if constexpr (EPI == 1) {
                    int rr = R & 16383;
                    int ii = rr >> 7, jj = rr & 127;
                    size_t kb = ((size_t)b * 65536 + (size_t)(2 * ii) * 256 + 2 * jj) * 256 + c;
                    float ka = key[kb];
                    float kb2 = key[kb + 256];
                    float kc2 = key[kb + 65536];
                    float kd2 = key[kb + 65536 + 256];
                    float low = 0.5f * (ka + kb2 + kc2 + kd2);
                    float high = 0.5f * (3.f * kd2 - ka - kb2 - kc2);
                    float wei = 1.f / (1.f + __expf(-(x + gv[n])));
                    ((ushort*)Outp)[(size_t)R * 256 + c] = f2bf(wei * high + low);
                } else if constexpr (EPI == 2) {
                    ((float*)Outp)[(size_t)R * 256 + c] = (x > 0.f) ? x + 1.f : __expf(x);
                } else {
                    ((float*)Outp)[(size_t)R * 256 + c] = x;
                }
            }
        }
    }
}

// ---------------- KV partials (fp32 in) ----------------
__global__ __launch_bounds__(256) void k_kv_part(const float* __restrict__ Km,
                                                 const float* __restrict__ Vn,
                                                 float* __restrict__ kvp,
                                                 float* __restrict__ ksp) {
    __shared__ float Kl[8][33];
    __shared__ float Vl[8][33];
    int t = threadIdx.x;
    int c = blockIdx.x & 31, h = (blockIdx.x >> 5) & 7, b = blockIdx.x >> 8;
    int d = t >> 3, vq = (t & 7) * 4;
    int lr = t >> 5, lc = t & 31;
    float acc0 = 0, acc1 = 0, acc2 = 0, acc3 = 0, ks = 0;
    size_t rowbase = (size_t)b * 16384 + (size_t)c * 512;
    for (int s0 = 0; s0 < 512; s0 += 8) {
        size_t idx = (rowbase + s0 + lr) * 256 + h * 32 + lc;
        Kl[lr][lc] = Km[idx];
        Vl[lr][lc] = Vn[idx];
        __syncthreads();
#pragma unroll
        for (int rr = 0; rr < 8; rr++) {
            float kd = Kl[rr][d];
            acc0 += kd * Vl[rr][vq];
            acc1 += kd * Vl[rr][vq + 1];
            acc2 += kd * Vl[rr][vq + 2];
            acc3 += kd * Vl[rr][vq + 3];
            ks += kd;
        }
        __syncthreads();
    }
    size_t ob = ((size_t)(b * 8 + h) * 32 + c) * 1024 + d * 32 + vq;
    kvp[ob] = acc0; kvp[ob + 1] = acc1; kvp[ob + 2] = acc2; kvp[ob + 3] = acc3;
    if ((t & 7) == 0) ksp[((b * 8 + h) * 32 + c) * 32 + d] = ks;
}

// ---------------- KV reduce -> bf16 augmented B^T: KVt[bh][48][32] ----------------
__global__ __launch_bounds__(256) void k_kv_reduce(const float* __restrict__ kvp,
                                                   const float* __restrict__ ksp,
                                                   ushort* __restrict__ kvt) {
    int bh = blockIdx.x, t = threadIdx.x;
    for (int e = t; e < 1024; e += 256) {
        float s = 0.f;
        for (int cc = 0; cc < 32; cc++) s += kvp[((size_t)bh * 32 + cc) * 1024 + e];
        int d = e >> 5, v = e & 31;
        kvt[((size_t)bh * 48 + v) * 32 + d] = f2bf(s);
    }
    if (t < 32) {
        float s = 0.f;
        for (int cc = 0; cc < 32; cc++) s += ksp[(bh * 32 + cc) * 32 + t];
        kvt[((size_t)bh * 48 + 32) * 32 + t] = f2bf(s);
    }
    for (int z = t; z < 480; z += 256) kvt[(size_t)bh * 48 * 32 + 33 * 32 + z] = 0;
}

// ---------------- MFMA q-GEMM (M=131072, K=512, N=256) + linear-attn epilogue ----------------
__global__ __launch_bounds__(256) void k_qattn_mfma(const float* __restrict__ query,
                                                    const ushort* __restrict__ wfp,
                                                    const float* __restrict__ qb,
                                                    const ushort* __restrict__ kvt,
                                                    float* __restrict__ Out) {
    __shared__ __align__(16) ushort smem[16384];  // As 8KB | Bs 8KB; Qs overlays 32KB after
    ushort* As = smem;
    ushort* Bs = smem + 4096;

    const int tid = threadIdx.x;
    const int lane = tid & 63;
    const int wid = tid >> 6;
    const int wrow = wid >> 1, wcol = wid & 1;
    const int bx = blockIdx.x & 1;
    const int by = blockIdx.x >> 1;
    const int r0 = by * 128;
    const int n0 = bx * 128;
    const int l15 = lane & 15, l4 = lane >> 4;

    const int loff = lane * 16;
    char* ldsB0 = (char*)Bs + wid * 2048;
    char* ldsB1 = (char*)Bs + wid * 2048 + 1024;

    const int srow = tid >> 1;
    const int shalf = tid & 1;
    const size_t agbase = (size_t)(r0 + srow) * 512 + shalf * 16;

    f32x4 acc[4][4];
#pragma unroll
    for (int i = 0; i < 4; i++)
#pragma unroll
        for (int j = 0; j < 4; j++) acc[i][j] = (f32x4){0.f, 0.f, 0.f, 0.f};

    for (int ks = 0; ks < 16; ks++) {
        // stage B via DMA (pre-tiled 8KB panel)
        const char* btile = (const char*)wfp + (size_t)(bx * 16 + ks) * 8192;
        gload16(btile + wid * 2048 + loff, ldsB0);
        gload16(btile + wid * 2048 + 1024 + loff, ldsB1);
        // stage A (fp32 -> bf16)
        {
            float f[16];
#pragma unroll
            for (int i = 0; i < 4; i++) {
                float4 t4 = *(const float4*)(query + agbase + (size_t)ks * 32 + i * 4);
                f[i * 4 + 0] = t4.x; f[i * 4 + 1] = t4.y; f[i * 4 + 2] = t4.z; f[i * 4 + 3] = t4.w;
            }
            unsigned int wd[8];
#pragma unroll
            for (int i = 0; i < 8; i++)
                wd[i] = (unsigned int)f2bf(f[2 * i]) | ((unsigned int)f2bf(f[2 * i + 1]) << 16);
            uint4 lo = {wd[0], wd[1], wd[2], wd[3]}, hi = {wd[4], wd[5], wd[6], wd[7]};
            *(uint4*)((char*)As + srow * 64 + shalf * 32) = lo;
            *(uint4*)((char*)As + srow * 64 + shalf * 32 + 16) = hi;
        }
        __syncthreads();

        short8v a[4], bfr[4];
#pragma unroll
        for (int m = 0; m < 4; m++)
            a[m] = *(const short8v*)((const char*)As + (wrow * 64 + m * 16 + l15) * 64 + l4 * 16);
#pragma unroll
        for (int n = 0; n < 4; n++)
            bfr[n] = *(const short8v*)((const char*)Bs + (wcol * 64 + n * 16 + l15) * 64 + l4 * 16);
#pragma unroll
        for (int m = 0; m < 4; m++)
#pragma unroll
            for (int n = 0; n < 4; n++)
                acc[m][n] = __builtin_amdgcn_mfma_f32_16x16x32_bf16(a[m], bfr[n], acc[m][n], 0, 0, 0);
        __syncthreads();
    }

    // Q = elu(x+qb)+1 -> Qs bf16 [128][128], XOR-swizzled (byte ^= (row&7)<<4)
    float qbv[4];
#pragma unroll
    for (int n = 0; n < 4; n++) qbv[n] = qb[n0 + wcol * 64 + n * 16 + l15];
#pragma unroll
    for (int m = 0; m < 4; m++) {
#pragma unroll
        for (int n = 0; n < 4; n++) {
#pragma unroll
            for (int r = 0; r < 4; r++) {
                int rl = wrow * 64 + m * 16 + l4 * 4 + r;
                int cl = wcol * 64 + n * 16 + l15;
                float x = acc[m][n][r] + qbv[n];
                float q = x > 0.f ? x + 1.f : __expf(x);
                int byte = (rl * 256 + cl * 2) ^ ((rl & 7) << 4);
                *(ushort*)((char*)smem + byte) = f2bf(q);
            }
        }
    }
    __syncthreads();

    // attention epilogue: per head O = Q_h @ KV_aug (48 cols: 32 KV, col32 = Ksum)
    const int bb = r0 >> 16;
#pragma unroll
    for (int hi = 0; hi < 2; hi++) {
        int h = bx * 4 + wcol * 2 + hi;
        int bh = bb * 8 + h;
        const ushort* kb = kvt + (size_t)bh * 48 * 32;
        short8v bk0 = *(const short8v*)(kb + (0 * 16 + l15) * 32 + l4 * 8);
        short8v bk1 = *(const short8v*)(kb + (1 * 16 + l15) * 32 + l4 * 8);
        short8v bkz = *(const short8v*)(kb + (2 * 16 + l15) * 32 + l4 * 8);
#pragma unroll
        for (int m = 0; m < 4; m++) {
            int rl = wrow * 64 + m * 16 + l15;
            int byte = (rl * 256 + wcol * 128 + hi * 64 + l4 * 16) ^ ((rl & 7) << 4);
            short8v aq = *(const short8v*)((const char*)smem + byte);
            f32x4 zero = (f32x4){0.f, 0.f, 0.f, 0.f};
            f32x4 o0 = __builtin_amdgcn_mfma_f32_16x16x32_bf16(aq, bk0, zero, 0, 0, 0);
            f32x4 o1 = __builtin_amdgcn_mfma_f32_16x16x32_bf16(aq, bk1, zero, 0, 0, 0);
            f32x4 oz = __builtin_amdgcn_mfma_f32_16x16x32_bf16(aq, bkz, zero, 0, 0, 0);
#pragma unroll
            for (int r = 0; r < 4; r++) {
                float z = __shfl(oz[r], (lane & 48));
                float sc = 1.f / (z + 1e-6f);
                int grow = r0 + wrow * 64 + m * 16 + l4 * 4 + r;
                int gcol = n0 + wcol * 64 + hi * 32 + l15;
                Out[(size_t)grow * 256 + gcol] = o0[r] * sc;
                Out[(size_t)grow * 256 + gcol + 16] = o1[r] * sc;
            }
        }
    }
}

extern "C" void kernel_launch(void* const* d_in, const int* in_sizes, int n_in,
                              void* d_out, int out_size, void* d_ws, size_t ws_size,
                              hipStream_t stream) {
    const float* query = (const float*)d_in[0];
    const float* key = (const float*)d_in[1];
    // d_in[2] = value: only its shape is used by the reference — never read.
    const float* mh = (const float*)d_in[3];
    const float* q_w = (const float*)d_in[4];
    const float* q_b = (const float*)d_in[5];
    const float* k_w = (const float*)d_in[6];
    const float* k_b = (const float*)d_in[7];
    const float* v_w = (const float*)d_in[8];
    const float* v_b = (const float*)d_in[9];
    const float* l1_w = (const float*)d_in[10];
    const float* l1_b = (const float*)d_in[11];
    const float* l2_w = (const float*)d_in[12];
    const float* l2_b = (const float*)d_in[13];
    const float* g1_w = (const float*)d_in[14];
    const float* g1_b = (const float*)d_in[15];
    const float* g2_w = (const float*)d_in[16];
    const float* g2_b = (const float*)d_in[17];

    float* out = (float*)d_out;
    float* ws = (float*)d_ws;

    float* ppart = ws + WS_PPART;
    float* pool = ws + WS_POOL;
    float* glob = ws + WS_GLOB;
    float* kvp = ws + WS_KVP;
    float* ksp = ws + WS_KSP;
    ushort* kvt = (ushort*)(ws + WS_KVT);
    ushort* wfp = (ushort*)(ws + WS_WFP);
    ushort* l1t = (ushort*)(ws + WS_L1T);
    ushort* l2t = (ushort*)(ws + WS_L2T);
    ushort* kwt = (ushort*)(ws + WS_KWT);
    ushort* vwt = (ushort*)(ws + WS_VWT);

    // big intermediates inside d_out (qattn overwrites everything at the end)
    ushort* t = (ushort*)out;                   // 32768x256 bf16
    ushort* fre = (ushort*)(out + 4194304);     // 32768x256 bf16
    float* Km = out + 8388608;                  // 32768x256 f32
    float* Vn = out + 16777216;                 // 32768x256 f32

    k_wprep<<<1024, 256, 0, stream>>>(l1_w, l2_w, k_w, v_w, l1t, l2t, kwt, vwt);
    k_wfuse<<<512, 256, 0, stream>>>(mh, q_w, wfp);
    k_pool<<<256, 256, 0, stream>>>(key, ppart);
    k_pool2<<<2, 256, 0, stream>>>(ppart, pool);
    k_glob<<<1, 256, 0, stream>>>(pool, g1_w, g1_b, g2_w, g2_b, glob);

    // t = relu(s @ l1_w + l1_b)            (s gathered from key)
    gemm_bf<1, 0><<<512, 256, 0, stream>>>(key, l1t, l1_b, t, nullptr, nullptr);
    // fre = sigmoid(t @ l2_w + l2_b + glob) * high + low
    gemm_bf<0, 1><<<512, 256, 0, stream>>>(t, l2t, l2_b, fre, glob, key);
    // Km = elu(fre @ k_w + k_b) + 1        (fp32 out)
    gemm_bf<0, 2><<<512, 256, 0, stream>>>(fre, kwt, k_b, Km, nullptr, nullptr);
    // Vn = fre @ v_w + v_b                 (fp32 out, /16384 folded away)
    gemm_bf<0, 3><<<512, 256, 0, stream>>>(fre, vwt, v_b, Vn, nullptr, nullptr);

    k_kv_part<<<512, 256, 0, stream>>>(Km, Vn, kvp, ksp);
    k_kv_reduce<<<16, 256, 0, stream>>>(kvp, ksp, kvt);

    k_qattn_mfma<<<2048, 256, 0, stream>>>(query, wfp, q_b, kvt, out);
}

// Round 4
// 271.564 us; speedup vs baseline: 6.3548x; 1.1864x over previous
//
#include <hip/hip_runtime.h>
#include <math.h>

// Problem constants
#define BB 2
#define N1 65536
#define N2 16384
#define CC 256
#define GG 512
#define NH 8
#define DH 32

// ws layout (float offsets)
#define WS_PPART 0         // 2*128*256 pool partials
#define WS_GLOB  66048     // 2*256
#define WS_KVP   66560     // 2*8*32*1024 KV partials
#define WS_KSP   590848    // 2*8*32*32 Ksum partials
#define WS_KVT   607232    // bf16 KV_aug: 16*48*32 ushort = 12288 floats
#define WS_WFP   619520    // bf16 Wf pre-tiled [16][256][32]: 131072 ushort = 65536 floats
#define WS_L1T   685056    // bf16 l1 pre-tiled: 2*8*128*32 ushort = 32768 floats
#define WS_L2T   717824
#define WS_KWT   750592
#define WS_VWT   783360

typedef __attribute__((ext_vector_type(8))) short short8v;
typedef __attribute__((ext_vector_type(4))) float f32x4;

__device__ __forceinline__ ushort f2bf(float x) {
    union { float f; unsigned int u; } v; v.f = x;
    unsigned int u = v.u;
    unsigned int r = (u + 0x7fffu + ((u >> 16) & 1u)) >> 16;
    return (ushort)r;
}

__device__ __forceinline__ float bf2f(ushort x) {
    union { float f; unsigned int u; } v;
    v.u = ((unsigned int)x) << 16;
    return v.f;
}

// packed f32x2 -> bf16x2 (RNE), 1 VALU op
__device__ __forceinline__ unsigned int cvtpk(float lo, float hi) {
    unsigned int d;
    asm("v_cvt_pk_bf16_f32 %0, %1, %2" : "=v"(d) : "v"(lo), "v"(hi));
    return d;
}

// async global->LDS, 16B per lane; lds base must be wave-uniform
__device__ __forceinline__ void gload16(const void* g, void* l) {
    __builtin_amdgcn_global_load_lds(
        (const __attribute__((address_space(1))) unsigned int*)g,
        (__attribute__((address_space(3))) unsigned int*)l, 16, 0, 0);
}

// ---------------- merged prep: weight tiling + Wf fuse + pool partials ----------------
// blocks 0..1023: tile l1/l2/kw/vw ([k][n] f32 -> [(n>>7)][(k>>5)][n&127][k&31] bf16)
// blocks 1024..1535: Wf = mh @ qw, tiled [g>>5][n][g&31] (full-N panels)
// blocks 1536..1791: pool partials (gather d-quadrant rows of key)
__global__ __launch_bounds__(256) void k_prep(const float* __restrict__ l1w, const float* __restrict__ l2w,
                                              const float* __restrict__ kw, const float* __restrict__ vw,
                                              const float* __restrict__ mh, const float* __restrict__ qw,
                                              const float* __restrict__ key,
                                              ushort* __restrict__ t0, ushort* __restrict__ t1,
                                              ushort* __restrict__ t2, ushort* __restrict__ t3,
                                              ushort* __restrict__ wfp, float* __restrict__ ppart) {
    int blk = blockIdx.x, t = threadIdx.x;
    if (blk < 1024) {
        int mat = blk >> 8, k = blk & 255, n = t;
        const float* w = mat == 0 ? l1w : mat == 1 ? l2w : mat == 2 ? kw : vw;
        ushort* o = mat == 0 ? t0 : mat == 1 ? t1 : mat == 2 ? t2 : t3;
        o[(((size_t)(n >> 7) * 8 + (k >> 5)) * 128 + (n & 127)) * 32 + (k & 31)] = f2bf(w[k * 256 + n]);
    } else if (blk < 1536) {
        __shared__ float mr[256];
        int g = blk - 1024;
        mr[t] = mh[g * 256 + t];
        __syncthreads();
        float acc = 0.f;
        for (int k = 0; k < 256; k++) acc += mr[k] * qw[k * 256 + t];
        wfp[(((size_t)(g >> 5) * 256 + t) * 32 + (g & 31))] = f2bf(acc);
    } else {
        int p = blk - 1536;
        int b = p >> 7, ci = p & 127;
        float acc = 0.f;
        for (int q = 0; q < 128; q++) {
            size_t idx = ((size_t)b * 65536 + (size_t)(2 * ci + 1) * 256 + (2 * q + 1)) * 256 + t;
            acc += key[idx];
        }
        ppart[(size_t)p * 256 + t] = acc;
    }
}

// ---------------- pool reduce + glob (single block) ----------------
__global__ __launch_bounds__(256) void k_glob2(const float* __restrict__ ppart,
                                               const float* __restrict__ g1w,
                                               const float* __restrict__ g1b,
                                               const float* __restrict__ g2w,
                                               const float* __restrict__ g2b,
                                               float* __restrict__ glob) {
    __shared__ float pl[256], hid[256];
    int t = threadIdx.x;
    for (int b = 0; b < BB; b++) {
        float s = 0.f;
        for (int p = 0; p < 128; p++) s += ppart[((size_t)b * 128 + p) * 256 + t];
        pl[t] = s * (2.f / 16384.f);
        __syncthreads();
        float acc = g1b[t];
        for (int k = 0; k < 256; k++) acc += pl[k] * g1w[k * 256 + t];
        hid[t] = fmaxf(acc, 0.f);
        __syncthreads();
        float a2 = g2b[t];
        for (int k = 0; k < 256; k++) a2 += hid[k] * g2w[k * 256 + t];
        glob[b * 256 + t] = a2;
        __syncthreads();
    }
}

// ---------------- bf16 MFMA mid GEMM: 128x128 tile, K=256, M=32768 ----------------
// AMODE 0: A = bf16 rows [m][256].  AMODE 1: A gathered from key (fp32, x2, -> bf16).
// EPI 0: relu->bf16  EPI 1: fre epilogue->bf16  EPI 4: elu+1->bf16  EPI 5: identity->bf16
template <int AMODE, int EPI>
__global__ __launch_bounds__(256) void gemm_bf(const void* __restrict__ Asrc_,
                                               const ushort* __restrict__ Wt,
                                               const float* __restrict__ bias,
                                               void* __restrict__ Outp,
                                               const float* __restrict__ glob,
                                               const float* __restrict__ key) {
    __shared__ __align__(16) ushort smem[8192];   // As 8KB | Bs 8KB
    ushort* As = smem;
    ushort* Bs = smem + 4096;

    const int tid = threadIdx.x;
    const int lane = tid & 63;
    const int w = tid >> 6;
    const int wrow = w >> 1, wcol = w & 1;
    const int bx = blockIdx.x & 1;
    const int by = blockIdx.x >> 1;
    const int r0 = by * 128, n0 = bx * 128;
    const int l15 = lane & 15, l4 = lane >> 4;

    const int loff = lane * 16;
    char* ldsB0 = (char*)Bs + w * 2048;
    char* ldsB1 = (char*)Bs + w * 2048 + 1024;
    const int rowA0 = w * 32 + (lane >> 2);
    const int kbA = (lane & 3) * 16;
    char* ldsA0 = (char*)As + w * 2048;
    char* ldsA1 = (char*)As + w * 2048 + 1024;
    const int srow = tid >> 1, shalf = tid & 1;
    size_t agbase = 0;
    if constexpr (AMODE == 1) {
        int r = r0 + srow;
        int b = r >> 14, rr = r & 16383;
        int ii = rr >> 7, jj = rr & 127;
        agbase = ((size_t)b * 65536 + (size_t)(2 * ii + 1) * 256 + (2 * jj + 1)) * 256 + shalf * 16;
    }

    f32x4 acc[4][4];
#pragma unroll
    for (int i = 0; i < 4; i++)
#pragma unroll
        for (int j = 0; j < 4; j++) acc[i][j] = (f32x4){0.f, 0.f, 0.f, 0.f};

    for (int ks = 0; ks < 8; ks++) {
        const char* btile = (const char*)Wt + (size_t)(bx * 8 + ks) * 8192;
        gload16(btile + w * 2048 + loff, ldsB0);
        gload16(btile + w * 2048 + 1024 + loff, ldsB1);
        if constexpr (AMODE == 0) {
            const char* ab = (const char*)Asrc_;
            gload16(ab + (size_t)(r0 + rowA0) * 512 + ks * 64 + kbA, ldsA0);
            gload16(ab + (size_t)(r0 + rowA0 + 16) * 512 + ks * 64 + kbA, ldsA1);
        } else {
            const float* kf = (const float*)Asrc_;
            float4 f0 = *(const float4*)(kf + agbase + (size_t)ks * 32);
            float4 f1 = *(const float4*)(kf + agbase + (size_t)ks * 32 + 4);
            float4 f2 = *(const float4*)(kf + agbase + (size_t)ks * 32 + 8);
            float4 f3 = *(const float4*)(kf + agbase + (size_t)ks * 32 + 12);
            uint4 lo = {cvtpk(f0.x * 2.f, f0.y * 2.f), cvtpk(f0.z * 2.f, f0.w * 2.f),
                        cvtpk(f1.x * 2.f, f1.y * 2.f), cvtpk(f1.z * 2.f, f1.w * 2.f)};
            uint4 hi = {cvtpk(f2.x * 2.f, f2.y * 2.f), cvtpk(f2.z * 2.f, f2.w * 2.f),
                        cvtpk(f3.x * 2.f, f3.y * 2.f), cvtpk(f3.z * 2.f, f3.w * 2.f)};
            *(uint4*)((char*)As + srow * 64 + shalf * 32) = lo;
            *(uint4*)((char*)As + srow * 64 + shalf * 32 + 16) = hi;
        }
        __syncthreads();

        short8v a[4], bfr[4];
#pragma unroll
        for (int m = 0; m < 4; m++)
            a[m] = *(const short8v*)((const char*)As + (wrow * 64 + m * 16 + l15) * 64 + l4 * 16);
#pragma unroll
        for (int n = 0; n < 4; n++)
            bfr[n] = *(const short8v*)((const char*)Bs + (wcol * 64 + n * 16 + l15) * 64 + l4 * 16);
#pragma unroll
        for (int m = 0; m < 4; m++)
#pragma unroll
            for (int n = 0; n < 4; n++)
                acc[m][n] = __builtin_amdgcn_mfma_f32_16x16x32_bf16(a[m], bfr[n], acc[m][n], 0, 0, 0);
        __syncthreads();
    }

    // epilogue
    const int b = r0 >> 14;
    float bv[4], gv[4];
#pragma unroll
    for (int n = 0; n < 4; n++) {
        int c = n0 + wcol * 64 + n * 16 + l15;
        bv[n] = bias[c];
        if constexpr (EPI == 1) gv[n] = glob[b * 256 + c];
    }
#pragma unroll
    for (int m = 0; m < 4; m++) {
#pragma unroll
        for (int n = 0; n < 4; n++) {
            int c = n0 + wcol * 64 + n * 16 + l15;
#pragma unroll
            for (int r = 0; r < 4; r++) {
                int row = wrow * 64 + m * 16 + l4 * 4 + r;
                int R = r0 + row;
                float x = acc[m][n][r] + bv[n];
                if constexpr (EPI == 0) {
                    ((ushort*)Outp)[(size_t)R * 256 + c] = f2bf(fmaxf(x, 0.f));
                } else if constexpr (EPI == 1) {
                    int rr = R & 16383;
                    int ii = rr >> 7, jj = rr & 127;
                    size_t kb = ((size_t)b * 65536 + (size_t)(2 * ii) * 256 + 2 * jj) * 256 + c;
                    float ka = key[kb];
                    float kb2 = key[kb + 256];
                    float kc2 = key[kb + 65536];
                    float kd2 = key[kb + 65536 + 256];
                    float low = 0.5f * (ka + kb2 + kc2 + kd2);
                    float high = 0.5f * (3.f * kd2 - ka - kb2 - kc2);
                    float wei = 1.f / (1.f + __expf(-(x + gv[n])));
                    ((ushort*)Outp)[(size_t)R * 256 + c] = f2bf(wei * high + low);
                } else if constexpr (EPI == 4) {
                    ((ushort*)Outp)[(size_t)R * 256 + c] = f2bf((x > 0.f) ? x + 1.f : __expf(x));
                } else {
                    ((ushort*)Outp)[(size_t)R * 256 + c] = f2bf(x);
                }
            }
        }
    }
}

// ---------------- KV partials (bf16 in) ----------------
__global__ __launch_bounds__(256) void k_kv_part(const ushort* __restrict__ Km,
                                                 const ushort* __restrict__ Vn,
                                                 float* __restrict__ kvp,
                                                 float* __restrict__ ksp) {
    __shared__ float Kl[8][33];
    __shared__ float Vl[8][33];
    int t = threadIdx.x;
    int c = blockIdx.x & 31, h = (blockIdx.x >> 5) & 7, b = blockIdx.x >> 8;
    int d = t >> 3, vq = (t & 7) * 4;
    int lr = t >> 5, lc = t & 31;
    float acc0 = 0, acc1 = 0, acc2 = 0, acc3 = 0, ks = 0;
    size_t rowbase = (size_t)b * 16384 + (size_t)c * 512;
    for (int s0 = 0; s0 < 512; s0 += 8) {
        size_t idx = (rowbase + s0 + lr) * 256 + h * 32 + lc;
        Kl[lr][lc] = bf2f(Km[idx]);
        Vl[lr][lc] = bf2f(Vn[idx]);
        __syncthreads();
#pragma unroll
        for (int rr = 0; rr < 8; rr++) {
            float kd = Kl[rr][d];
            acc0 += kd * Vl[rr][vq];
            acc1 += kd * Vl[rr][vq + 1];
            acc2 += kd * Vl[rr][vq + 2];
            acc3 += kd * Vl[rr][vq + 3];
            ks += kd;
        }
        __syncthreads();
    }
    size_t ob = ((size_t)(b * 8 + h) * 32 + c) * 1024 + d * 32 + vq;
    kvp[ob] = acc0; kvp[ob + 1] = acc1; kvp[ob + 2] = acc2; kvp[ob + 3] = acc3;
    if ((t & 7) == 0) ksp[((b * 8 + h) * 32 + c) * 32 + d] = ks;
}

// ---------------- KV reduce -> bf16 augmented B^T: KVt[bh][48][32] ----------------
__global__ __launch_bounds__(256) void k_kv_reduce(const float* __restrict__ kvp,
                                                   const float* __restrict__ ksp,
                                                   ushort* __restrict__ kvt) {
    int bh = blockIdx.x, t = threadIdx.x;
    for (int e = t; e < 1024; e += 256) {
        float s = 0.f;
        for (int cc = 0; cc < 32; cc++) s += kvp[((size_t)bh * 32 + cc) * 1024 + e];
        int d = e >> 5, v = e & 31;
        kvt[((size_t)bh * 48 + v) * 32 + d] = f2bf(s);
    }
    if (t < 32) {
        float s = 0.f;
        for (int cc = 0; cc < 32; cc++) s += ksp[(bh * 32 + cc) * 32 + t];
        kvt[((size_t)bh * 48 + 32) * 32 + t] = f2bf(s);
    }
    for (int z = t; z < 480; z += 256) kvt[(size_t)bh * 48 * 32 + 33 * 32 + z] = 0;
}

// ---------------- MFMA q-GEMM (M=131072, K=512, N=256, BM=128 BN=256) + attn epilogue ----------------
// 512 threads, 8 waves (2 wrow x 4 wcol), each wave 64x64.
__global__ __launch_bounds__(512, 4) void k_qattn_mfma(const float* __restrict__ query,
                                                       const ushort* __restrict__ wfp,
                                                       const float* __restrict__ qb,
                                                       const ushort* __restrict__ kvt,
                                                       float* __restrict__ Out) {
    __shared__ __align__(16) ushort smem[32768];  // 64KB: As 8KB | Bs 16KB; Qs overlays after
    ushort* As = smem;
    ushort* Bs = smem + 4096;

    const int tid = threadIdx.x;
    const int lane = tid & 63;
    const int wid = tid >> 6;            // 0..7
    const int wrow = wid >> 2, wcol = wid & 3;
    const int by = blockIdx.x;
    const int r0 = by * 128;
    const int l15 = lane & 15, l4 = lane >> 4;

    const int loff = lane * 16;
    char* ldsB0 = (char*)Bs + wid * 2048;
    char* ldsB1 = (char*)Bs + wid * 2048 + 1024;

    const int srow = tid >> 2;           // 0..127
    const int skq = tid & 3;             // which 8-float chunk of the 32-k step
    const size_t agbase = (size_t)(r0 + srow) * 512 + skq * 8;

    f32x4 acc[4][4];
#pragma unroll
    for (int i = 0; i < 4; i++)
#pragma unroll
        for (int j = 0; j < 4; j++) acc[i][j] = (f32x4){0.f, 0.f, 0.f, 0.f};

    for (int ks = 0; ks < 16; ks++) {
        // B: pre-tiled [ks][256][32] bf16 panel, 16KB, pure DMA
        const char* btile = (const char*)wfp + (size_t)ks * 16384;
        gload16(btile + wid * 2048 + loff, ldsB0);
        gload16(btile + wid * 2048 + 1024 + loff, ldsB1);
        // A: fp32 -> bf16 via cvt_pk, one b128 LDS write per thread
        {
            float4 f0 = *(const float4*)(query + agbase + (size_t)ks * 32);
            float4 f1 = *(const float4*)(query + agbase + (size_t)ks * 32 + 4);
            uint4 pk = {cvtpk(f0.x, f0.y), cvtpk(f0.z, f0.w),
                        cvtpk(f1.x, f1.y), cvtpk(f1.z, f1.w)};
            *(uint4*)((char*)As + srow * 64 + skq * 16) = pk;
        }
        __syncthreads();

        short8v a[4], bfr[4];
#pragma unroll
        for (int m = 0; m < 4; m++)
            a[m] = *(const short8v*)((const char*)As + (wrow * 64 + m * 16 + l15) * 64 + l4 * 16);
#pragma unroll
        for (int n = 0; n < 4; n++)
            bfr[n] = *(const short8v*)((const char*)Bs + (wcol * 64 + n * 16 + l15) * 64 + l4 * 16);
#pragma unroll
        for (int m = 0; m < 4; m++)
#pragma unroll
            for (int n = 0; n < 4; n++)
                acc[m][n] = __builtin_amdgcn_mfma_f32_16x16x32_bf16(a[m], bfr[n], acc[m][n], 0, 0, 0);
        __syncthreads();
    }

    // Q = elu(x+qb)+1 -> per-wave Qs region [64][64] bf16, XOR-swizzled
    float qbv[4];
#pragma unroll
    for (int n = 0; n < 4; n++) qbv[n] = qb[wcol * 64 + n * 16 + l15];
#pragma unroll
    for (int m = 0; m < 4; m++) {
#pragma unroll
        for (int n = 0; n < 4; n++) {
#pragma unroll
            for (int r = 0; r < 4; r++) {
                int rl = m * 16 + l4 * 4 + r;
                int cl = n * 16 + l15;
                float x = acc[m][n][r] + qbv[n];
                float q = x > 0.f ? x + 1.f : __expf(x);
                int byte = wid * 8192 + ((rl * 128 + cl * 2) ^ ((rl & 7) << 4));
                *(ushort*)((char*)smem + byte) = f2bf(q);
            }
        }
    }
    __syncthreads();

    // attention epilogue: wave's 2 heads (wcol*2, wcol*2+1); O = Q_h @ KV_aug
    const int bb = r0 >> 16;
#pragma unroll
    for (int hi = 0; hi < 2; hi++) {
        int h = wcol * 2 + hi;
        int bh = bb * 8 + h;
        const ushort* kb = kvt + (size_t)bh * 48 * 32;
        short8v bk0 = *(const short8v*)(kb + (0 * 16 + l15) * 32 + l4 * 8);
        short8v bk1 = *(const short8v*)(kb + (1 * 16 + l15) * 32 + l4 * 8);
        short8v bkz = *(const short8v*)(kb + (2 * 16 + l15) * 32 + l4 * 8);
#pragma unroll
        for (int m = 0; m < 4; m++) {
            int rl = m * 16 + l15;
            int byte = wid * 8192 + ((rl * 128 + hi * 64 + l4 * 16) ^ ((rl & 7) << 4));
            short8v aq = *(const short8v*)((const char*)smem + byte);
            f32x4 zero = (f32x4){0.f, 0.f, 0.f, 0.f};
            f32x4 o0 = __builtin_amdgcn_mfma_f32_16x16x32_bf16(aq, bk0, zero, 0, 0, 0);
            f32x4 o1 = __builtin_amdgcn_mfma_f32_16x16x32_bf16(aq, bk1, zero, 0, 0, 0);
            f32x4 oz = __builtin_amdgcn_mfma_f32_16x16x32_bf16(aq, bkz, zero, 0, 0, 0);
#pragma unroll
            for (int r = 0; r < 4; r++) {
                float z = __shfl(oz[r], (lane & 48));
                float sc = 1.f / (z + 1e-6f);
                int grow = r0 + wrow * 64 + m * 16 + l4 * 4 + r;
                int gcol = wcol * 64 + hi * 32 + l15;
                Out[(size_t)grow * 256 + gcol] = o0[r] * sc;
                Out[(size_t)grow * 256 + gcol + 16] = o1[r] * sc;
            }
        }
    }
}

extern "C" void kernel_launch(void* const* d_in, const int* in_sizes, int n_in,
                              void* d_out, int out_size, void* d_ws, size_t ws_size,
                              hipStream_t stream) {
    const float* query = (const float*)d_in[0];
    const float* key = (const float*)d_in[1];
    // d_in[2] = value: only its shape is used by the reference — never read.
    const float* mh = (const float*)d_in[3];
    const float* q_w = (const float*)d_in[4];
    const float* q_b = (const float*)d_in[5];
    const float* k_w = (const float*)d_in[6];
    const float* k_b = (const float*)d_in[7];
    const float* v_w = (const float*)d_in[8];
    const float* v_b = (const float*)d_in[9];
    const float* l1_w = (const float*)d_in[10];
    const float* l1_b = (const float*)d_in[11];
    const float* l2_w = (const float*)d_in[12];
    const float* l2_b = (const float*)d_in[13];
    const float* g1_w = (const float*)d_in[14];
    const float* g1_b = (const float*)d_in[15];
    const float* g2_w = (const float*)d_in[16];
    const float* g2_b = (const float*)d_in[17];

    float* out = (float*)d_out;
    float* ws = (float*)d_ws;

    float* ppart = ws + WS_PPART;
    float* glob = ws + WS_GLOB;
    float* kvp = ws + WS_KVP;
    float* ksp = ws + WS_KSP;
    ushort* kvt = (ushort*)(ws + WS_KVT);
    ushort* wfp = (ushort*)(ws + WS_WFP);
    ushort* l1t = (ushort*)(ws + WS_L1T);
    ushort* l2t = (ushort*)(ws + WS_L2T);
    ushort* kwt = (ushort*)(ws + WS_KWT);
    ushort* vwt = (ushort*)(ws + WS_VWT);

    // big intermediates inside d_out (qattn overwrites everything at the end)
    ushort* t = (ushort*)out;                      // 32768x256 bf16
    ushort* fre = (ushort*)(out + 4194304);        // 32768x256 bf16
    ushort* Km = (ushort*)(out + 8388608);         // 32768x256 bf16
    ushort* Vn = (ushort*)(out + 12582912);        // 32768x256 bf16

    k_prep<<<1792, 256, 0, stream>>>(l1_w, l2_w, k_w, v_w, mh, q_w, key,
                                     l1t, l2t, kwt, vwt, wfp, ppart);
    k_glob2<<<1, 256, 0, stream>>>(ppart, g1_w, g1_b, g2_w, g2_b, glob);

    // t = relu(s @ l1_w + l1_b)            (s gathered from key)
    gemm_bf<1, 0><<<512, 256, 0, stream>>>(key, l1t, l1_b, t, nullptr, nullptr);
    // fre = sigmoid(t @ l2_w + l2_b + glob) * high + low
    gemm_bf<0, 1><<<512, 256, 0, stream>>>(t, l2t, l2_b, fre, glob, key);
    // Km = elu(fre @ k_w + k_b) + 1        (bf16 out)
    gemm_bf<0, 4><<<512, 256, 0, stream>>>(fre, kwt, k_b, Km, nullptr, nullptr);
    // Vn = fre @ v_w + v_b                 (bf16 out, /16384 folded away)
    gemm_bf<0, 5><<<512, 256, 0, stream>>>(fre, vwt, v_b, Vn, nullptr, nullptr);

    k_kv_part<<<512, 256, 0, stream>>>(Km, Vn, kvp, ksp);
    k_kv_reduce<<<16, 256, 0, stream>>>(kvp, ksp, kvt);

    k_qattn_mfma<<<1024, 512, 0, stream>>>(query, wfp, q_b, kvt, out);
}